// Round 1
// baseline (275.620 us; speedup 1.0000x reference)
//
#include <hip/hip_runtime.h>
#include <stdint.h>

typedef __attribute__((ext_vector_type(8))) __bf16 bf16x8;
typedef __attribute__((ext_vector_type(4))) float f32x4;

#define SEQ 2048
#define DMODEL 1024
#define NHEAD 16
#define HDIM 64
#define BTOK 4096   // B*S
#define NQKV 3072   // stacked q,k,v output cols

// ---- async global->LDS, 16B per lane; LDS dest must be wave-linear ----
__device__ __forceinline__ void gload_lds16(const __bf16* g, __bf16* l) {
  __builtin_amdgcn_global_load_lds(
      (__attribute__((address_space(1))) void*)const_cast<__bf16*>(g),
      (__attribute__((address_space(3))) void*)l, 16, 0, 0);
}

__device__ __forceinline__ f32x4 mfma16(bf16x8 a, bf16x8 b, f32x4 c) {
  return __builtin_amdgcn_mfma_f32_16x16x32_bf16(a, b, c, 0, 0, 0);
}

// swizzled 16B-fragment pointer into a tile with 128B rows (64 bf16/row).
// byte = row*128 + 16*(c16 ^ (row&7))  -- matches the inverse-swizzled staging.
__device__ __forceinline__ const bf16x8* frag128(const __bf16* tile, int row, int c16) {
  return reinterpret_cast<const bf16x8*>(tile) + ((row << 3) + (c16 ^ (row & 7)));
}

// ---------------- fp32 -> bf16 convert, 8 elems/thread ----------------
__global__ __launch_bounds__(256) void cvt_f32_bf16(const float* __restrict__ in,
                                                    __bf16* __restrict__ out, int n8) {
  int i = blockIdx.x * 256 + threadIdx.x;
  if (i >= n8) return;
  const float4* p = reinterpret_cast<const float4*>(in) + (size_t)i * 2;
  float4 a = p[0], b = p[1];
  bf16x8 o;
  o[0] = (__bf16)a.x; o[1] = (__bf16)a.y; o[2] = (__bf16)a.z; o[3] = (__bf16)a.w;
  o[4] = (__bf16)b.x; o[5] = (__bf16)b.y; o[6] = (__bf16)b.z; o[7] = (__bf16)b.w;
  reinterpret_cast<bf16x8*>(out)[i] = o;
}

// ------------- C = A(4096xK) * Bw(NxK)^T + bias, m97-class -------------
// MODE 0: N=3072, scatter into q (B,H,S,Hd), k (B,H,S,Hd), v^T (B,H,Hd,S), bf16
// MODE 1: N=1024, fp32 out + bias
template <int MODE>
__global__ __launch_bounds__(256) void gemm_bt(
    const __bf16* __restrict__ A, const __bf16* __restrict__ Bw,
    const float* __restrict__ bias0, const float* __restrict__ bias1,
    const float* __restrict__ bias2,
    __bf16* __restrict__ qo, __bf16* __restrict__ ko, __bf16* __restrict__ vo,
    float* __restrict__ outf) {
  constexpr int K = DMODEL;
  __shared__ __bf16 Alds[128][32];
  __shared__ __bf16 Blds[128][32];
  const int t = threadIdx.x;
  const int lane = t & 63;
  const int wr = (t >> 6) >> 1, wc = (t >> 6) & 1;
  const int bm0 = blockIdx.x * 128, bn0 = blockIdx.y * 128;

  f32x4 acc[4][4] = {};
  for (int k0 = 0; k0 < K; k0 += 32) {
    __syncthreads();
#pragma unroll
    for (int i = 0; i < 2; ++i) {
      int c = t + i * 256;               // 512 x 16B chunks per tile
      int row = c >> 2, kof = (c & 3) << 3;
      gload_lds16(A + (size_t)(bm0 + row) * K + k0 + kof, &Alds[0][0] + c * 8);
      gload_lds16(Bw + (size_t)(bn0 + row) * K + k0 + kof, &Blds[0][0] + c * 8);
    }
    __syncthreads();
    bf16x8 af[4], bfr[4];
#pragma unroll
    for (int m = 0; m < 4; ++m)
      af[m] = *(const bf16x8*)&Alds[wr * 64 + m * 16 + (lane & 15)][(lane >> 4) * 8];
#pragma unroll
    for (int n = 0; n < 4; ++n)
      bfr[n] = *(const bf16x8*)&Blds[wc * 64 + n * 16 + (lane & 15)][(lane >> 4) * 8];
#pragma unroll
    for (int m = 0; m < 4; ++m)
#pragma unroll
      for (int n = 0; n < 4; ++n)
        acc[m][n] = mfma16(af[m], bfr[n], acc[m][n]);
  }

  const int r0 = bm0 + wr * 64, c0 = bn0 + wc * 64;
#pragma unroll
  for (int m = 0; m < 4; ++m) {
#pragma unroll
    for (int n = 0; n < 4; ++n) {
#pragma unroll
      for (int r = 0; r < 4; ++r) {
        int gm = r0 + m * 16 + (lane >> 4) * 4 + r;  // token
        int gn = c0 + n * 16 + (lane & 15);          // output col
        float v = acc[m][n][r];
        if (MODE == 0) {
          int which = gn >> 10, j = gn & 1023;
          int h = j >> 6, d = j & 63;
          int b = gm >> 11, s = gm & 2047;
          int bh = b * NHEAD + h;
          if (which == 0)
            qo[((size_t)bh * SEQ + s) * HDIM + d] = (__bf16)(v + bias0[j]);
          else if (which == 1)
            ko[((size_t)bh * SEQ + s) * HDIM + d] = (__bf16)(v + bias1[j]);
          else
            vo[((size_t)bh * HDIM + d) * SEQ + s] = (__bf16)(v + bias2[j]);
        } else {
          outf[(size_t)gm * DMODEL + gn] = v + bias0[gn];
        }
      }
    }
  }
}

// --------------------- flash attention, keep k >= q ---------------------
// grid: (S/64 q-tiles, B*H). 4 waves x 16 q-rows. K/V tiles of 64 keys.
__global__ __launch_bounds__(256) void attn_fwd(const __bf16* __restrict__ qg,
                                                const __bf16* __restrict__ kg,
                                                const __bf16* __restrict__ vtg,
                                                __bf16* __restrict__ att) {
  __shared__ __bf16 Qlds[64][64];
  __shared__ __bf16 Klds[64][64];
  __shared__ __bf16 Vtld[64][64];      // [d][k]
  __shared__ __bf16 Plds[4][16][64];   // wave-private
  const int t = threadIdx.x, lane = t & 63, w = t >> 6;
  const int qt = blockIdx.x, bh = blockIdx.y;
  const int q0 = qt * 64;
  const __bf16* qbase = qg + ((size_t)bh * SEQ + q0) * HDIM;
  const __bf16* kbase = kg + (size_t)bh * SEQ * HDIM;
  const __bf16* vbase = vtg + (size_t)bh * HDIM * SEQ;

  // stage Q once (inverse-swizzled source, linear LDS dest)
#pragma unroll
  for (int i = 0; i < 2; ++i) {
    int c = t + i * 256;
    int row = c >> 3, sc = (c & 7) ^ (row & 7);
    gload_lds16(qbase + row * HDIM + sc * 8, &Qlds[0][0] + c * 8);
  }

  float mrow[4], lrow[4];
  f32x4 acco[4] = {};
#pragma unroll
  for (int r = 0; r < 4; ++r) { mrow[r] = -3.0e38f; lrow[r] = 0.f; }
  const float scale = 0.03125f;  // 1/sqrt(1024)
  __bf16* Pw = &Plds[w][0][0];

  for (int kt = qt; kt < SEQ / 64; ++kt) {
    __syncthreads();  // previous tile's reads done
#pragma unroll
    for (int i = 0; i < 2; ++i) {
      int c = t + i * 256;
      int row = c >> 3, sc = (c & 7) ^ (row & 7);
      gload_lds16(kbase + ((size_t)kt * 64 + row) * HDIM + sc * 8, &Klds[0][0] + c * 8);
      gload_lds16(vbase + (size_t)row * SEQ + kt * 64 + sc * 8, &Vtld[0][0] + c * 8);
    }
    __syncthreads();  // staging (incl. first-iter Q) drained

    // S = Q K^T  (16 q-rows x 64 keys per wave)
    f32x4 sacc[4] = {};
    bf16x8 qf[2];
#pragma unroll
    for (int kk = 0; kk < 2; ++kk)
      qf[kk] = *frag128(&Qlds[0][0], w * 16 + (lane & 15), kk * 4 + (lane >> 4));
#pragma unroll
    for (int ni = 0; ni < 4; ++ni)
#pragma unroll
      for (int kk = 0; kk < 2; ++kk)
        sacc[ni] = mfma16(qf[kk],
                          *frag128(&Klds[0][0], ni * 16 + (lane & 15), kk * 4 + (lane >> 4)),
                          sacc[ni]);

    // scale + mask (keep k >= q); only the diagonal tile is partial
    float sv[4][4];
    const bool diag = (kt == qt);
    const int qrl = w * 16 + (lane >> 4) * 4;
#pragma unroll
    for (int ni = 0; ni < 4; ++ni) {
      int kcl = ni * 16 + (lane & 15);
#pragma unroll
      for (int r = 0; r < 4; ++r) {
        float x = sacc[ni][r] * scale;
        if (diag && kcl < qrl + r) x = -3.0e38f;
        sv[ni][r] = x;
      }
    }
    // online softmax; row r lives on the 16 lanes sharing (lane>>4)
    float corr[4];
#pragma unroll
    for (int r = 0; r < 4; ++r) {
      float mx = fmaxf(fmaxf(sv[0][r], sv[1][r]), fmaxf(sv[2][r], sv[3][r]));
#pragma unroll
      for (int off = 1; off < 16; off <<= 1) mx = fmaxf(mx, __shfl_xor(mx, off));
      float newm = fmaxf(mrow[r], mx);
      corr[r] = __expf(mrow[r] - newm);
      mrow[r] = newm;
      float s = 0.f;
#pragma unroll
      for (int ni = 0; ni < 4; ++ni) {
        float pv = __expf(sv[ni][r] - newm);
        sv[ni][r] = pv;
        s += pv;
      }
#pragma unroll
      for (int off = 1; off < 16; off <<= 1) s += __shfl_xor(s, off);
      lrow[r] = lrow[r] * corr[r] + s;
    }
#pragma unroll
    for (int n = 0; n < 4; ++n)
#pragma unroll
      for (int r = 0; r < 4; ++r) acco[n][r] *= corr[r];

    // P -> LDS (swizzled, wave-private)
#pragma unroll
    for (int ni = 0; ni < 4; ++ni) {
#pragma unroll
      for (int r = 0; r < 4; ++r) {
        int prow = (lane >> 4) * 4 + r, pcol = ni * 16 + (lane & 15);
        *(__bf16*)((char*)Pw + (prow * 128 + (((pcol * 2)) ^ ((prow & 7) << 4)))) =
            (__bf16)sv[ni][r];
      }
    }
    // O += P V  (Vt rows are d -> contiguous B-fragments)
#pragma unroll
    for (int kk = 0; kk < 2; ++kk) {
      bf16x8 pf = *frag128(Pw, lane & 15, kk * 4 + (lane >> 4));
#pragma unroll
      for (int n = 0; n < 4; ++n)
        acco[n] = mfma16(pf,
                         *frag128(&Vtld[0][0], n * 16 + (lane & 15), kk * 4 + (lane >> 4)),
                         acco[n]);
    }
  }

  const int b = bh >> 4, h = bh & 15;
#pragma unroll
  for (int r = 0; r < 4; ++r) {
    int qrow = q0 + w * 16 + (lane >> 4) * 4 + r;
    float inv = 1.0f / lrow[r];
#pragma unroll
    for (int n = 0; n < 4; ++n) {
      att[((size_t)(b * SEQ + qrow)) * DMODEL + h * HDIM + n * 16 + (lane & 15)] =
          (__bf16)(acco[n][r] * inv);
    }
  }
}

extern "C" void kernel_launch(void* const* d_in, const int* in_sizes, int n_in,
                              void* d_out, int out_size, void* d_ws, size_t ws_size,
                              hipStream_t stream) {
  (void)in_sizes; (void)n_in; (void)out_size;
  const float* x  = (const float*)d_in[0];
  const float* Wq = (const float*)d_in[1];
  const float* bq = (const float*)d_in[2];
  const float* Wk = (const float*)d_in[3];
  const float* bk = (const float*)d_in[4];
  const float* Wv = (const float*)d_in[5];
  const float* bv = (const float*)d_in[6];
  const float* Wo = (const float*)d_in[7];
  const float* bo = (const float*)d_in[8];
  float* out = (float*)d_out;

  const size_t SZ_X = (size_t)BTOK * DMODEL;  // 4M elems
  const size_t SZ_W = (size_t)DMODEL * DMODEL;
  const size_t SZ_H = (size_t)32 * SEQ * HDIM;  // B*H * S * Hd

  char* p = (char*)d_ws;
  __bf16* x_bf  = (__bf16*)p; p += SZ_X * 2;
  __bf16* wqkv  = (__bf16*)p; p += 3 * SZ_W * 2;
  __bf16* wo_bf = (__bf16*)p; p += SZ_W * 2;
  __bf16* q_bf  = (__bf16*)p; p += SZ_H * 2;
  __bf16* k_bf  = (__bf16*)p; p += SZ_H * 2;
  __bf16* vt_bf = (__bf16*)p; p += SZ_H * 2;
  __bf16* at_bf = (__bf16*)p; p += SZ_X * 2;
  if ((size_t)(p - (char*)d_ws) > ws_size) return;  // ws too small: leave output poisoned

  cvt_f32_bf16<<<(unsigned)(SZ_X / 8 / 256), 256, 0, stream>>>(x, x_bf, (int)(SZ_X / 8));
  cvt_f32_bf16<<<(unsigned)(SZ_W / 8 / 256), 256, 0, stream>>>(Wq, wqkv, (int)(SZ_W / 8));
  cvt_f32_bf16<<<(unsigned)(SZ_W / 8 / 256), 256, 0, stream>>>(Wk, wqkv + SZ_W, (int)(SZ_W / 8));
  cvt_f32_bf16<<<(unsigned)(SZ_W / 8 / 256), 256, 0, stream>>>(Wv, wqkv + 2 * SZ_W, (int)(SZ_W / 8));
  cvt_f32_bf16<<<(unsigned)(SZ_W / 8 / 256), 256, 0, stream>>>(Wo, wo_bf, (int)(SZ_W / 8));

  gemm_bt<0><<<dim3(BTOK / 128, NQKV / 128), 256, 0, stream>>>(
      x_bf, wqkv, bq, bk, bv, q_bf, k_bf, vt_bf, nullptr);
  attn_fwd<<<dim3(SEQ / 64, 32), 256, 0, stream>>>(q_bf, k_bf, vt_bf, at_bf);
  gemm_bt<1><<<dim3(BTOK / 128, DMODEL / 128), 256, 0, stream>>>(
      at_bf, wo_bf, bo, nullptr, nullptr, nullptr, nullptr, nullptr, out);
}

// Round 2
// 228.122 us; speedup vs baseline: 1.2082x; 1.2082x over previous
//
#include <hip/hip_runtime.h>
#include <stdint.h>

typedef __attribute__((ext_vector_type(8))) __bf16 bf16x8;
typedef __attribute__((ext_vector_type(4))) float f32x4;

#define SEQ 2048
#define DMODEL 1024
#define NHEAD 16
#define HDIM 64
#define BTOK 4096   // B*S
#define NQKV 3072   // stacked q,k,v output cols

// ---- async global->LDS, 16B per lane; LDS dest must be wave-linear ----
__device__ __forceinline__ void gload_lds16(const __bf16* g, __bf16* l) {
  __builtin_amdgcn_global_load_lds(
      (__attribute__((address_space(1))) void*)const_cast<__bf16*>(g),
      (__attribute__((address_space(3))) void*)l, 16, 0, 0);
}

__device__ __forceinline__ f32x4 mfma16(bf16x8 a, bf16x8 b, f32x4 c) {
  return __builtin_amdgcn_mfma_f32_16x16x32_bf16(a, b, c, 0, 0, 0);
}

// swizzled 16B-fragment pointer into a tile with 128B rows (64 bf16/row).
// byte = row*128 + 16*(c16 ^ (row&7))  -- matches the inverse-swizzled staging.
__device__ __forceinline__ const bf16x8* frag128(const __bf16* tile, int row, int c16) {
  return reinterpret_cast<const bf16x8*>(tile) + ((row << 3) + (c16 ^ (row & 7)));
}

// ---------------- fp32 -> bf16 convert, 8 elems/thread ----------------
__global__ __launch_bounds__(256) void cvt_f32_bf16(const float* __restrict__ in,
                                                    __bf16* __restrict__ out, int n8) {
  int i = blockIdx.x * 256 + threadIdx.x;
  if (i >= n8) return;
  const float4* p = reinterpret_cast<const float4*>(in) + (size_t)i * 2;
  float4 a = p[0], b = p[1];
  bf16x8 o;
  o[0] = (__bf16)a.x; o[1] = (__bf16)a.y; o[2] = (__bf16)a.z; o[3] = (__bf16)a.w;
  o[4] = (__bf16)b.x; o[5] = (__bf16)b.y; o[6] = (__bf16)b.z; o[7] = (__bf16)b.w;
  reinterpret_cast<bf16x8*>(out)[i] = o;
}

// ------------- C = A(4096xK) * Bw(NxK)^T + bias, m97-class -------------
// MODE 0: N=3072, scatter into q,k,v all natural (B,H,S,Hd) bf16
// MODE 1: N=1024, fp32 out + bias
template <int MODE>
__global__ __launch_bounds__(256) void gemm_bt(
    const __bf16* __restrict__ A, const __bf16* __restrict__ Bw,
    const float* __restrict__ bias0, const float* __restrict__ bias1,
    const float* __restrict__ bias2,
    __bf16* __restrict__ qo, __bf16* __restrict__ ko, __bf16* __restrict__ vo,
    float* __restrict__ outf) {
  constexpr int K = DMODEL;
  __shared__ __bf16 Alds[128][32];
  __shared__ __bf16 Blds[128][32];
  const int t = threadIdx.x;
  const int lane = t & 63;
  const int wr = (t >> 6) >> 1, wc = (t >> 6) & 1;
  const int bm0 = blockIdx.x * 128, bn0 = blockIdx.y * 128;

  f32x4 acc[4][4] = {};
  for (int k0 = 0; k0 < K; k0 += 32) {
    __syncthreads();
#pragma unroll
    for (int i = 0; i < 2; ++i) {
      int c = t + i * 256;               // 512 x 16B chunks per tile
      int row = c >> 2, kof = (c & 3) << 3;
      gload_lds16(A + (size_t)(bm0 + row) * K + k0 + kof, &Alds[0][0] + c * 8);
      gload_lds16(Bw + (size_t)(bn0 + row) * K + k0 + kof, &Blds[0][0] + c * 8);
    }
    __syncthreads();
    bf16x8 af[4], bfr[4];
#pragma unroll
    for (int m = 0; m < 4; ++m)
      af[m] = *(const bf16x8*)&Alds[wr * 64 + m * 16 + (lane & 15)][(lane >> 4) * 8];
#pragma unroll
    for (int n = 0; n < 4; ++n)
      bfr[n] = *(const bf16x8*)&Blds[wc * 64 + n * 16 + (lane & 15)][(lane >> 4) * 8];
#pragma unroll
    for (int m = 0; m < 4; ++m)
#pragma unroll
      for (int n = 0; n < 4; ++n)
        acc[m][n] = mfma16(af[m], bfr[n], acc[m][n]);
  }

  const int r0 = bm0 + wr * 64, c0 = bn0 + wc * 64;
#pragma unroll
  for (int m = 0; m < 4; ++m) {
#pragma unroll
    for (int n = 0; n < 4; ++n) {
#pragma unroll
      for (int r = 0; r < 4; ++r) {
        int gm = r0 + m * 16 + (lane >> 4) * 4 + r;  // token
        int gn = c0 + n * 16 + (lane & 15);          // output col
        float v = acc[m][n][r];
        if (MODE == 0) {
          int which = gn >> 10, j = gn & 1023;
          int h = j >> 6, d = j & 63;
          int b = gm >> 11, s = gm & 2047;
          size_t off = ((size_t)(b * NHEAD + h) * SEQ + s) * HDIM + d;
          if (which == 0)
            qo[off] = (__bf16)(v + bias0[j]);
          else if (which == 1)
            ko[off] = (__bf16)(v + bias1[j]);
          else
            vo[off] = (__bf16)(v + bias2[j]);
        } else {
          outf[(size_t)gm * DMODEL + gn] = v + bias0[gn];
        }
      }
    }
  }
}

// ------- v (BH,S,Hd) -> vt (BH,Hd,S), LDS-tiled 64x64 transpose -------
__global__ __launch_bounds__(256) void transpose_v(const __bf16* __restrict__ v,
                                                   __bf16* __restrict__ vt) {
  __shared__ __bf16 T[64][80];  // row stride 160B = 10x16 (16B-aligned, bank-spread)
  const int s0 = blockIdx.x * 64;
  const int bh = blockIdx.y;
  const int t = threadIdx.x;
  const __bf16* src = v + ((size_t)bh * SEQ + s0) * HDIM;
#pragma unroll
  for (int p = 0; p < 2; ++p) {
    int c = t + p * 256;          // 512 chunks of 8 elems
    int r = c >> 3, d0 = (c & 7) << 3;
    *(bf16x8*)&T[r][d0] = *(const bf16x8*)(src + (size_t)r * HDIM + d0);
  }
  __syncthreads();
#pragma unroll
  for (int p = 0; p < 2; ++p) {
    int c = t + p * 256;
    int d = c & 63, sc = (c >> 6) << 3;   // d = lane -> conflict-free column reads
    bf16x8 o;
#pragma unroll
    for (int j = 0; j < 8; ++j) o[j] = T[sc + j][d];
    *(bf16x8*)(vt + ((size_t)bh * HDIM + d) * SEQ + s0 + sc) = o;
  }
}

// --------------------- flash attention, keep k >= q ---------------------
// grid: (x = B*H so bh pins to XCD bh%8, y = S/64 q-tiles). 4 waves x 16 q-rows.
__global__ __launch_bounds__(256) void attn_fwd(const __bf16* __restrict__ qg,
                                                const __bf16* __restrict__ kg,
                                                const __bf16* __restrict__ vtg,
                                                __bf16* __restrict__ att) {
  __shared__ __bf16 Qlds[64][64];
  __shared__ __bf16 Klds[64][64];
  __shared__ __bf16 Vtld[64][64];      // [d][k]
  __shared__ __bf16 Plds[4][16][64];   // wave-private
  const int t = threadIdx.x, lane = t & 63, w = t >> 6;
  const int bh = blockIdx.x, qt = blockIdx.y;
  const int q0 = qt * 64;
  const __bf16* qbase = qg + ((size_t)bh * SEQ + q0) * HDIM;
  const __bf16* kbase = kg + (size_t)bh * SEQ * HDIM;
  const __bf16* vbase = vtg + (size_t)bh * HDIM * SEQ;

  // stage Q once (inverse-swizzled source, linear LDS dest)
#pragma unroll
  for (int i = 0; i < 2; ++i) {
    int c = t + i * 256;
    int row = c >> 3, sc = (c & 7) ^ (row & 7);
    gload_lds16(qbase + row * HDIM + sc * 8, &Qlds[0][0] + c * 8);
  }

  float mrow[4], lrow[4];
  f32x4 acco[4] = {};
#pragma unroll
  for (int r = 0; r < 4; ++r) { mrow[r] = -3.0e38f; lrow[r] = 0.f; }
  const float scale = 0.03125f;  // 1/sqrt(1024)
  __bf16* Pw = &Plds[w][0][0];

  for (int kt = qt; kt < SEQ / 64; ++kt) {
    __syncthreads();  // previous tile's reads done
#pragma unroll
    for (int i = 0; i < 2; ++i) {
      int c = t + i * 256;
      int row = c >> 3, sc = (c & 7) ^ (row & 7);
      gload_lds16(kbase + ((size_t)kt * 64 + row) * HDIM + sc * 8, &Klds[0][0] + c * 8);
      gload_lds16(vbase + (size_t)row * SEQ + kt * 64 + sc * 8, &Vtld[0][0] + c * 8);
    }
    __syncthreads();  // staging (incl. first-iter Q) drained

    // S = Q K^T  (16 q-rows x 64 keys per wave)
    f32x4 sacc[4] = {};
    bf16x8 qf[2];
#pragma unroll
    for (int kk = 0; kk < 2; ++kk)
      qf[kk] = *frag128(&Qlds[0][0], w * 16 + (lane & 15), kk * 4 + (lane >> 4));
#pragma unroll
    for (int ni = 0; ni < 4; ++ni)
#pragma unroll
      for (int kk = 0; kk < 2; ++kk)
        sacc[ni] = mfma16(qf[kk],
                          *frag128(&Klds[0][0], ni * 16 + (lane & 15), kk * 4 + (lane >> 4)),
                          sacc[ni]);

    // scale; mask only on the diagonal tile (uniform branch)
    float sv[4][4];
#pragma unroll
    for (int ni = 0; ni < 4; ++ni)
#pragma unroll
      for (int r = 0; r < 4; ++r) sv[ni][r] = sacc[ni][r] * scale;
    if (kt == qt) {
      const int qrl = w * 16 + (lane >> 4) * 4;
#pragma unroll
      for (int ni = 0; ni < 4; ++ni) {
        int kcl = ni * 16 + (lane & 15);
#pragma unroll
        for (int r = 0; r < 4; ++r)
          if (kcl < qrl + r) sv[ni][r] = -3.0e38f;
      }
    }
    // online softmax; row r lives on the 16 lanes sharing (lane>>4)
    float corr[4];
#pragma unroll
    for (int r = 0; r < 4; ++r) {
      float mx = fmaxf(fmaxf(sv[0][r], sv[1][r]), fmaxf(sv[2][r], sv[3][r]));
#pragma unroll
      for (int off = 1; off < 16; off <<= 1) mx = fmaxf(mx, __shfl_xor(mx, off));
      float newm = fmaxf(mrow[r], mx);
      corr[r] = __expf(mrow[r] - newm);
      mrow[r] = newm;
      float s = 0.f;
#pragma unroll
      for (int ni = 0; ni < 4; ++ni) {
        float pv = __expf(sv[ni][r] - newm);
        sv[ni][r] = pv;
        s += pv;
      }
#pragma unroll
      for (int off = 1; off < 16; off <<= 1) s += __shfl_xor(s, off);
      lrow[r] = lrow[r] * corr[r] + s;
    }
#pragma unroll
    for (int n = 0; n < 4; ++n)
#pragma unroll
      for (int r = 0; r < 4; ++r) acco[n][r] *= corr[r];

    // P -> LDS (swizzled, wave-private)
#pragma unroll
    for (int ni = 0; ni < 4; ++ni) {
#pragma unroll
      for (int r = 0; r < 4; ++r) {
        int prow = (lane >> 4) * 4 + r, pcol = ni * 16 + (lane & 15);
        *(__bf16*)((char*)Pw + (prow * 128 + (((pcol * 2)) ^ ((prow & 7) << 4)))) =
            (__bf16)sv[ni][r];
      }
    }
    // O += P V  (Vt rows are d -> contiguous B-fragments)
#pragma unroll
    for (int kk = 0; kk < 2; ++kk) {
      bf16x8 pf = *frag128(Pw, lane & 15, kk * 4 + (lane >> 4));
#pragma unroll
      for (int n = 0; n < 4; ++n)
        acco[n] = mfma16(pf,
                         *frag128(&Vtld[0][0], n * 16 + (lane & 15), kk * 4 + (lane >> 4)),
                         acco[n]);
    }
  }

  const int b = bh >> 4, h = bh & 15;
#pragma unroll
  for (int r = 0; r < 4; ++r) {
    int qrow = q0 + w * 16 + (lane >> 4) * 4 + r;
    float inv = 1.0f / lrow[r];
#pragma unroll
    for (int n = 0; n < 4; ++n) {
      att[((size_t)(b * SEQ + qrow)) * DMODEL + h * HDIM + n * 16 + (lane & 15)] =
          (__bf16)(acco[n][r] * inv);
    }
  }
}

extern "C" void kernel_launch(void* const* d_in, const int* in_sizes, int n_in,
                              void* d_out, int out_size, void* d_ws, size_t ws_size,
                              hipStream_t stream) {
  (void)in_sizes; (void)n_in; (void)out_size;
  const float* x  = (const float*)d_in[0];
  const float* Wq = (const float*)d_in[1];
  const float* bq = (const float*)d_in[2];
  const float* Wk = (const float*)d_in[3];
  const float* bk = (const float*)d_in[4];
  const float* Wv = (const float*)d_in[5];
  const float* bv = (const float*)d_in[6];
  const float* Wo = (const float*)d_in[7];
  const float* bo = (const float*)d_in[8];
  float* out = (float*)d_out;

  const size_t SZ_X = (size_t)BTOK * DMODEL;  // 4M elems
  const size_t SZ_W = (size_t)DMODEL * DMODEL;
  const size_t SZ_H = (size_t)32 * SEQ * HDIM;  // B*H * S * Hd

  char* p = (char*)d_ws;
  __bf16* x_bf  = (__bf16*)p; p += SZ_X * 2;   // reused as vt after gemm<0>
  __bf16* wqkv  = (__bf16*)p; p += 3 * SZ_W * 2;
  __bf16* wo_bf = (__bf16*)p; p += SZ_W * 2;
  __bf16* q_bf  = (__bf16*)p; p += SZ_H * 2;
  __bf16* k_bf  = (__bf16*)p; p += SZ_H * 2;
  __bf16* v_bf  = (__bf16*)p; p += SZ_H * 2;
  __bf16* at_bf = (__bf16*)p; p += SZ_X * 2;
  if ((size_t)(p - (char*)d_ws) > ws_size) return;  // ws too small: leave output poisoned
  __bf16* vt_bf = x_bf;  // x dead after gemm<0>

  cvt_f32_bf16<<<(unsigned)(SZ_X / 8 / 256), 256, 0, stream>>>(x, x_bf, (int)(SZ_X / 8));
  cvt_f32_bf16<<<(unsigned)(SZ_W / 8 / 256), 256, 0, stream>>>(Wq, wqkv, (int)(SZ_W / 8));
  cvt_f32_bf16<<<(unsigned)(SZ_W / 8 / 256), 256, 0, stream>>>(Wk, wqkv + SZ_W, (int)(SZ_W / 8));
  cvt_f32_bf16<<<(unsigned)(SZ_W / 8 / 256), 256, 0, stream>>>(Wv, wqkv + 2 * SZ_W, (int)(SZ_W / 8));
  cvt_f32_bf16<<<(unsigned)(SZ_W / 8 / 256), 256, 0, stream>>>(Wo, wo_bf, (int)(SZ_W / 8));

  gemm_bt<0><<<dim3(BTOK / 128, NQKV / 128), 256, 0, stream>>>(
      x_bf, wqkv, bq, bk, bv, q_bf, k_bf, v_bf, nullptr);
  transpose_v<<<dim3(SEQ / 64, 32), 256, 0, stream>>>(v_bf, vt_bf);
  attn_fwd<<<dim3(32, SEQ / 64), 256, 0, stream>>>(q_bf, k_bf, vt_bf, at_bf);
  gemm_bt<1><<<dim3(BTOK / 128, DMODEL / 128), 256, 0, stream>>>(
      at_bf, wo_bf, bo, nullptr, nullptr, nullptr, nullptr, nullptr, out);
}

// Round 3
// 221.939 us; speedup vs baseline: 1.2419x; 1.0279x over previous
//
#include <hip/hip_runtime.h>
#include <stdint.h>

typedef __attribute__((ext_vector_type(8))) __bf16 bf16x8;
typedef __attribute__((ext_vector_type(4))) float f32x4;

#define SEQ 2048
#define DMODEL 1024
#define NHEAD 16
#define HDIM 64
#define BTOK 4096   // B*S
#define NQKV 3072   // stacked q,k,v output cols

// ---- async global->LDS, 16B per lane; LDS dest must be wave-linear ----
__device__ __forceinline__ void gload_lds16(const __bf16* g, __bf16* l) {
  __builtin_amdgcn_global_load_lds(
      (__attribute__((address_space(1))) void*)const_cast<__bf16*>(g),
      (__attribute__((address_space(3))) void*)l, 16, 0, 0);
}

__device__ __forceinline__ f32x4 mfma16(bf16x8 a, bf16x8 b, f32x4 c) {
  return __builtin_amdgcn_mfma_f32_16x16x32_bf16(a, b, c, 0, 0, 0);
}

// swizzled 16B-fragment pointer into a tile with 128B rows (64 bf16/row).
// byte = row*128 + 16*(c16 ^ (row&7))  -- matches the inverse-swizzled staging.
__device__ __forceinline__ const bf16x8* frag128(const __bf16* tile, int row, int c16) {
  return reinterpret_cast<const bf16x8*>(tile) + ((row << 3) + (c16 ^ (row & 7)));
}

// ---------------- fp32 -> bf16 convert, 8 elems/thread ----------------
__global__ __launch_bounds__(256) void cvt_f32_bf16(const float* __restrict__ in,
                                                    __bf16* __restrict__ out, int n8) {
  int i = blockIdx.x * 256 + threadIdx.x;
  if (i >= n8) return;
  const float4* p = reinterpret_cast<const float4*>(in) + (size_t)i * 2;
  float4 a = p[0], b = p[1];
  bf16x8 o;
  o[0] = (__bf16)a.x; o[1] = (__bf16)a.y; o[2] = (__bf16)a.z; o[3] = (__bf16)a.w;
  o[4] = (__bf16)b.x; o[5] = (__bf16)b.y; o[6] = (__bf16)b.z; o[7] = (__bf16)b.w;
  reinterpret_cast<bf16x8*>(out)[i] = o;
}

// ---- 4 weight matrices (Wq,Wk,Wv,Wo) -> contiguous bf16 in one launch ----
__global__ __launch_bounds__(256) void cvt4_f32_bf16(const float* __restrict__ w0,
                                                     const float* __restrict__ w1,
                                                     const float* __restrict__ w2,
                                                     const float* __restrict__ w3,
                                                     __bf16* __restrict__ out, int n8per) {
  const int y = blockIdx.y;
  const float* src = (y == 0) ? w0 : (y == 1) ? w1 : (y == 2) ? w2 : w3;
  int i = blockIdx.x * 256 + threadIdx.x;
  if (i >= n8per) return;
  const float4* p = reinterpret_cast<const float4*>(src) + (size_t)i * 2;
  float4 a = p[0], b = p[1];
  bf16x8 o;
  o[0] = (__bf16)a.x; o[1] = (__bf16)a.y; o[2] = (__bf16)a.z; o[3] = (__bf16)a.w;
  o[4] = (__bf16)b.x; o[5] = (__bf16)b.y; o[6] = (__bf16)b.z; o[7] = (__bf16)b.w;
  reinterpret_cast<bf16x8*>(out)[(size_t)y * n8per + i] = o;
}

// ------------- C = A(4096xK) * Bw(NxK)^T + bias, m97-class -------------
// MODE 0: N=3072, scatter into q,k,v all natural (B,H,S,Hd) bf16
// MODE 1: N=1024, fp32 out + bias
template <int MODE>
__global__ __launch_bounds__(256) void gemm_bt(
    const __bf16* __restrict__ A, const __bf16* __restrict__ Bw,
    const float* __restrict__ bias0, const float* __restrict__ bias1,
    const float* __restrict__ bias2,
    __bf16* __restrict__ qo, __bf16* __restrict__ ko, __bf16* __restrict__ vo,
    float* __restrict__ outf) {
  constexpr int K = DMODEL;
  __shared__ __bf16 Alds[128][32];
  __shared__ __bf16 Blds[128][32];
  const int t = threadIdx.x;
  const int lane = t & 63;
  const int wr = (t >> 6) >> 1, wc = (t >> 6) & 1;
  const int bm0 = blockIdx.x * 128, bn0 = blockIdx.y * 128;

  f32x4 acc[4][4] = {};
  for (int k0 = 0; k0 < K; k0 += 32) {
    __syncthreads();
#pragma unroll
    for (int i = 0; i < 2; ++i) {
      int c = t + i * 256;               // 512 x 16B chunks per tile
      int row = c >> 2, kof = (c & 3) << 3;
      gload_lds16(A + (size_t)(bm0 + row) * K + k0 + kof, &Alds[0][0] + c * 8);
      gload_lds16(Bw + (size_t)(bn0 + row) * K + k0 + kof, &Blds[0][0] + c * 8);
    }
    __syncthreads();
    bf16x8 af[4], bfr[4];
#pragma unroll
    for (int m = 0; m < 4; ++m)
      af[m] = *(const bf16x8*)&Alds[wr * 64 + m * 16 + (lane & 15)][(lane >> 4) * 8];
#pragma unroll
    for (int n = 0; n < 4; ++n)
      bfr[n] = *(const bf16x8*)&Blds[wc * 64 + n * 16 + (lane & 15)][(lane >> 4) * 8];
    __builtin_amdgcn_s_setprio(1);
#pragma unroll
    for (int m = 0; m < 4; ++m)
#pragma unroll
      for (int n = 0; n < 4; ++n)
        acc[m][n] = mfma16(af[m], bfr[n], acc[m][n]);
    __builtin_amdgcn_s_setprio(0);
  }

  const int r0 = bm0 + wr * 64, c0 = bn0 + wc * 64;
#pragma unroll
  for (int m = 0; m < 4; ++m) {
#pragma unroll
    for (int n = 0; n < 4; ++n) {
#pragma unroll
      for (int r = 0; r < 4; ++r) {
        int gm = r0 + m * 16 + (lane >> 4) * 4 + r;  // token
        int gn = c0 + n * 16 + (lane & 15);          // output col
        float v = acc[m][n][r];
        if (MODE == 0) {
          int which = gn >> 10, j = gn & 1023;
          int h = j >> 6, d = j & 63;
          int b = gm >> 11, s = gm & 2047;
          size_t off = ((size_t)(b * NHEAD + h) * SEQ + s) * HDIM + d;
          if (which == 0)
            qo[off] = (__bf16)(v + bias0[j]);
          else if (which == 1)
            ko[off] = (__bf16)(v + bias1[j]);
          else
            vo[off] = (__bf16)(v + bias2[j]);
        } else {
          outf[(size_t)gm * DMODEL + gn] = v + bias0[gn];
        }
      }
    }
  }
}

// ------- v (BH,S,Hd) -> vt (BH,Hd,S), LDS-tiled 64x64 transpose -------
__global__ __launch_bounds__(256) void transpose_v(const __bf16* __restrict__ v,
                                                   __bf16* __restrict__ vt) {
  __shared__ __bf16 T[64][80];  // row stride 160B = 10x16 (16B-aligned, bank-spread)
  const int s0 = blockIdx.x * 64;
  const int bh = blockIdx.y;
  const int t = threadIdx.x;
  const __bf16* src = v + ((size_t)bh * SEQ + s0) * HDIM;
#pragma unroll
  for (int p = 0; p < 2; ++p) {
    int c = t + p * 256;          // 512 chunks of 8 elems
    int r = c >> 3, d0 = (c & 7) << 3;
    *(bf16x8*)&T[r][d0] = *(const bf16x8*)(src + (size_t)r * HDIM + d0);
  }
  __syncthreads();
#pragma unroll
  for (int p = 0; p < 2; ++p) {
    int c = t + p * 256;
    int d = c & 63, sc = (c >> 6) << 3;   // d = lane -> conflict-free column reads
    bf16x8 o;
#pragma unroll
    for (int j = 0; j < 8; ++j) o[j] = T[sc + j][d];
    *(bf16x8*)(vt + ((size_t)bh * HDIM + d) * SEQ + s0 + sc) = o;
  }
}

// --------------------- flash attention, keep k >= q ---------------------
// grid: (x = B*H so bh pins to XCD bh%8, y = S/64 q-tiles). 4 waves x 16 q-rows.
// K/V double-buffered: prefetch tile kt+1 issued before computing tile kt.
__global__ __launch_bounds__(256) void attn_fwd(const __bf16* __restrict__ qg,
                                                const __bf16* __restrict__ kg,
                                                const __bf16* __restrict__ vtg,
                                                __bf16* __restrict__ att) {
  __shared__ __bf16 Klds[2][64][64];
  __shared__ __bf16 Vtld[2][64][64];   // [d][k]
  __shared__ __bf16 Plds[4][16][64];   // wave-private
  const int t = threadIdx.x, lane = t & 63, w = t >> 6;
  const int bh = blockIdx.x, qt = blockIdx.y;
  const int q0 = qt * 64;
  const __bf16* qbase = qg + ((size_t)bh * SEQ + q0) * HDIM;
  const __bf16* kbase = kg + (size_t)bh * SEQ * HDIM;
  const __bf16* vbase = vtg + (size_t)bh * HDIM * SEQ;
  constexpr int NT = SEQ / 64;

  // Q fragments straight to registers (L2-resident; one-time cost)
  bf16x8 qf[2];
#pragma unroll
  for (int kk = 0; kk < 2; ++kk)
    qf[kk] = *(const bf16x8*)(qbase + (w * 16 + (lane & 15)) * HDIM + kk * 32 + (lane >> 4) * 8);

  // stage K/V tile kt into buffer buf (inverse-swizzled source, linear LDS dest)
  auto stage = [&](int kt_, int buf) {
#pragma unroll
    for (int i = 0; i < 2; ++i) {
      int c = t + i * 256;
      int row = c >> 3, sc = (c & 7) ^ (row & 7);
      gload_lds16(kbase + ((size_t)kt_ * 64 + row) * HDIM + sc * 8, &Klds[buf][0][0] + c * 8);
      gload_lds16(vbase + (size_t)row * SEQ + kt_ * 64 + sc * 8, &Vtld[buf][0][0] + c * 8);
    }
  };

  float mrow[4], lrow[4];
  f32x4 acco[4] = {};
#pragma unroll
  for (int r = 0; r < 4; ++r) { mrow[r] = -3.0e38f; lrow[r] = 0.f; }
  const float scale = 0.03125f;  // 1/sqrt(1024)
  __bf16* Pw = &Plds[w][0][0];

  stage(qt, 0);
  __syncthreads();  // prologue drain
  int cur = 0;

  for (int kt = qt; kt < NT; ++kt) {
    if (kt + 1 < NT) stage(kt + 1, cur ^ 1);  // prefetch: latency hides under compute

    // S = Q K^T  (16 q-rows x 64 keys per wave)
    f32x4 sacc[4] = {};
    __builtin_amdgcn_s_setprio(1);
#pragma unroll
    for (int ni = 0; ni < 4; ++ni)
#pragma unroll
      for (int kk = 0; kk < 2; ++kk)
        sacc[ni] = mfma16(qf[kk],
                          *frag128(&Klds[cur][0][0], ni * 16 + (lane & 15), kk * 4 + (lane >> 4)),
                          sacc[ni]);
    __builtin_amdgcn_s_setprio(0);

    // scale; mask only on the diagonal tile (uniform branch)
    float sv[4][4];
#pragma unroll
    for (int ni = 0; ni < 4; ++ni)
#pragma unroll
      for (int r = 0; r < 4; ++r) sv[ni][r] = sacc[ni][r] * scale;
    if (kt == qt) {
      const int qrl = w * 16 + (lane >> 4) * 4;
#pragma unroll
      for (int ni = 0; ni < 4; ++ni) {
        int kcl = ni * 16 + (lane & 15);
#pragma unroll
        for (int r = 0; r < 4; ++r)
          if (kcl < qrl + r) sv[ni][r] = -3.0e38f;
      }
    }
    // online softmax; row r lives on the 16 lanes sharing (lane>>4)
    float corr[4];
#pragma unroll
    for (int r = 0; r < 4; ++r) {
      float mx = fmaxf(fmaxf(sv[0][r], sv[1][r]), fmaxf(sv[2][r], sv[3][r]));
#pragma unroll
      for (int off = 1; off < 16; off <<= 1) mx = fmaxf(mx, __shfl_xor(mx, off));
      float newm = fmaxf(mrow[r], mx);
      corr[r] = __expf(mrow[r] - newm);
      mrow[r] = newm;
      float s = 0.f;
#pragma unroll
      for (int ni = 0; ni < 4; ++ni) {
        float pv = __expf(sv[ni][r] - newm);
        sv[ni][r] = pv;
        s += pv;
      }
#pragma unroll
      for (int off = 1; off < 16; off <<= 1) s += __shfl_xor(s, off);
      lrow[r] = lrow[r] * corr[r] + s;
    }
#pragma unroll
    for (int n = 0; n < 4; ++n)
#pragma unroll
      for (int r = 0; r < 4; ++r) acco[n][r] *= corr[r];

    // P -> LDS (swizzled, wave-private)
#pragma unroll
    for (int ni = 0; ni < 4; ++ni) {
#pragma unroll
      for (int r = 0; r < 4; ++r) {
        int prow = (lane >> 4) * 4 + r, pcol = ni * 16 + (lane & 15);
        *(__bf16*)((char*)Pw + (prow * 128 + (((pcol * 2)) ^ ((prow & 7) << 4)))) =
            (__bf16)sv[ni][r];
      }
    }
    // O += P V  (Vt rows are d -> contiguous B-fragments)
    __builtin_amdgcn_s_setprio(1);
#pragma unroll
    for (int kk = 0; kk < 2; ++kk) {
      bf16x8 pf = *frag128(Pw, lane & 15, kk * 4 + (lane >> 4));
#pragma unroll
      for (int n = 0; n < 4; ++n)
        acco[n] = mfma16(pf,
                         *frag128(&Vtld[cur][0][0], n * 16 + (lane & 15), kk * 4 + (lane >> 4)),
                         acco[n]);
    }
    __builtin_amdgcn_s_setprio(0);

    __syncthreads();  // drains prefetch vmcnt + protects buffer reuse
    cur ^= 1;
  }

  const int b = bh >> 4, h = bh & 15;
#pragma unroll
  for (int r = 0; r < 4; ++r) {
    int qrow = q0 + w * 16 + (lane >> 4) * 4 + r;
    float inv = 1.0f / lrow[r];
#pragma unroll
    for (int n = 0; n < 4; ++n) {
      att[((size_t)(b * SEQ + qrow)) * DMODEL + h * HDIM + n * 16 + (lane & 15)] =
          (__bf16)(acco[n][r] * inv);
    }
  }
}

extern "C" void kernel_launch(void* const* d_in, const int* in_sizes, int n_in,
                              void* d_out, int out_size, void* d_ws, size_t ws_size,
                              hipStream_t stream) {
  (void)in_sizes; (void)n_in; (void)out_size;
  const float* x  = (const float*)d_in[0];
  const float* Wq = (const float*)d_in[1];
  const float* bq = (const float*)d_in[2];
  const float* Wk = (const float*)d_in[3];
  const float* bk = (const float*)d_in[4];
  const float* Wv = (const float*)d_in[5];
  const float* bv = (const float*)d_in[6];
  const float* Wo = (const float*)d_in[7];
  const float* bo = (const float*)d_in[8];
  float* out = (float*)d_out;

  const size_t SZ_X = (size_t)BTOK * DMODEL;  // 4M elems
  const size_t SZ_W = (size_t)DMODEL * DMODEL;
  const size_t SZ_H = (size_t)32 * SEQ * HDIM;  // B*H * S * Hd

  char* p = (char*)d_ws;
  __bf16* x_bf  = (__bf16*)p; p += SZ_X * 2;   // reused as vt after gemm<0>
  __bf16* wqkv  = (__bf16*)p; p += 3 * SZ_W * 2;
  __bf16* wo_bf = (__bf16*)p; p += SZ_W * 2;   // contiguous after wqkv (cvt4 relies on it)
  __bf16* q_bf  = (__bf16*)p; p += SZ_H * 2;
  __bf16* k_bf  = (__bf16*)p; p += SZ_H * 2;
  __bf16* v_bf  = (__bf16*)p; p += SZ_H * 2;
  __bf16* at_bf = (__bf16*)p; p += SZ_X * 2;
  if ((size_t)(p - (char*)d_ws) > ws_size) return;  // ws too small: leave output poisoned
  __bf16* vt_bf = x_bf;  // x dead after gemm<0>

  cvt_f32_bf16<<<(unsigned)(SZ_X / 8 / 256), 256, 0, stream>>>(x, x_bf, (int)(SZ_X / 8));
  cvt4_f32_bf16<<<dim3((unsigned)(SZ_W / 8 / 256), 4), 256, 0, stream>>>(
      Wq, Wk, Wv, Wo, wqkv, (int)(SZ_W / 8));

  gemm_bt<0><<<dim3(BTOK / 128, NQKV / 128), 256, 0, stream>>>(
      x_bf, wqkv, bq, bk, bv, q_bf, k_bf, v_bf, nullptr);
  transpose_v<<<dim3(SEQ / 64, 32), 256, 0, stream>>>(v_bf, vt_bf);
  attn_fwd<<<dim3(32, SEQ / 64), 256, 0, stream>>>(q_bf, k_bf, vt_bf, at_bf);
  gemm_bt<1><<<dim3(BTOK / 128, DMODEL / 128), 256, 0, stream>>>(
      at_bf, wo_bf, bo, nullptr, nullptr, nullptr, nullptr, nullptr, out);
}

// Round 4
// 200.617 us; speedup vs baseline: 1.3739x; 1.1063x over previous
//
#include <hip/hip_runtime.h>
#include <stdint.h>

typedef __attribute__((ext_vector_type(8))) __bf16 bf16x8;
typedef __attribute__((ext_vector_type(4))) float f32x4;
typedef __attribute__((ext_vector_type(16))) float f32x16;
typedef __attribute__((ext_vector_type(4))) unsigned u32x4;

#define SEQ 2048
#define DMODEL 1024
#define NHEAD 16
#define HDIM 64
#define BTOK 4096   // B*S
#define NQKV 3072   // stacked q,k,v output cols

// ---- async global->LDS, 16B per lane; LDS dest must be wave-linear ----
__device__ __forceinline__ void gload_lds16(const __bf16* g, __bf16* l) {
  __builtin_amdgcn_global_load_lds(
      (__attribute__((address_space(1))) void*)const_cast<__bf16*>(g),
      (__attribute__((address_space(3))) void*)l, 16, 0, 0);
}

__device__ __forceinline__ f32x4 mfma16(bf16x8 a, bf16x8 b, f32x4 c) {
  return __builtin_amdgcn_mfma_f32_16x16x32_bf16(a, b, c, 0, 0, 0);
}
__device__ __forceinline__ f32x16 mfma32(bf16x8 a, bf16x8 b, f32x16 c) {
  return __builtin_amdgcn_mfma_f32_32x32x16_bf16(a, b, c, 0, 0, 0);
}

// pack 2 f32 -> 1 u32 of 2 bf16 (lo in low half)
__device__ __forceinline__ unsigned cvtpk(float lo, float hi) {
  unsigned r;
  asm("v_cvt_pk_bf16_f32 %0, %1, %2" : "=v"(r) : "v"(lo), "v"(hi));
  return r;
}
// swap a's lanes 32-63 with b's lanes 0-31 (in place)
__device__ __forceinline__ void plswap(unsigned& a, unsigned& b) {
  asm volatile("v_permlane32_swap_b32 %0, %1" : "+v"(a), "+v"(b));
}

// swizzled 16B-fragment pointer into a tile with 128B rows (64 bf16/row).
// byte = row*128 + 16*(c16 ^ (row&7))  -- matches the inverse-swizzled staging.
__device__ __forceinline__ const bf16x8* frag128(const __bf16* tile, int row, int c16) {
  return reinterpret_cast<const bf16x8*>(tile) + ((row << 3) + (c16 ^ (row & 7)));
}

// ---------------- fp32 -> bf16 convert, 8 elems/thread ----------------
__global__ __launch_bounds__(256) void cvt_f32_bf16(const float* __restrict__ in,
                                                    __bf16* __restrict__ out, int n8) {
  int i = blockIdx.x * 256 + threadIdx.x;
  if (i >= n8) return;
  const float4* p = reinterpret_cast<const float4*>(in) + (size_t)i * 2;
  float4 a = p[0], b = p[1];
  bf16x8 o;
  o[0] = (__bf16)a.x; o[1] = (__bf16)a.y; o[2] = (__bf16)a.z; o[3] = (__bf16)a.w;
  o[4] = (__bf16)b.x; o[5] = (__bf16)b.y; o[6] = (__bf16)b.z; o[7] = (__bf16)b.w;
  reinterpret_cast<bf16x8*>(out)[i] = o;
}

// ---- 4 weight matrices (Wq,Wk,Wv,Wo) -> contiguous bf16 in one launch ----
__global__ __launch_bounds__(256) void cvt4_f32_bf16(const float* __restrict__ w0,
                                                     const float* __restrict__ w1,
                                                     const float* __restrict__ w2,
                                                     const float* __restrict__ w3,
                                                     __bf16* __restrict__ out, int n8per) {
  const int y = blockIdx.y;
  const float* src = (y == 0) ? w0 : (y == 1) ? w1 : (y == 2) ? w2 : w3;
  int i = blockIdx.x * 256 + threadIdx.x;
  if (i >= n8per) return;
  const float4* p = reinterpret_cast<const float4*>(src) + (size_t)i * 2;
  float4 a = p[0], b = p[1];
  bf16x8 o;
  o[0] = (__bf16)a.x; o[1] = (__bf16)a.y; o[2] = (__bf16)a.z; o[3] = (__bf16)a.w;
  o[4] = (__bf16)b.x; o[5] = (__bf16)b.y; o[6] = (__bf16)b.z; o[7] = (__bf16)b.w;
  reinterpret_cast<bf16x8*>(out)[(size_t)y * n8per + i] = o;
}

// ------------- C = A(4096xK) * Bw(NxK)^T + bias, m97-class -------------
template <int MODE>
__global__ __launch_bounds__(256) void gemm_bt(
    const __bf16* __restrict__ A, const __bf16* __restrict__ Bw,
    const float* __restrict__ bias0, const float* __restrict__ bias1,
    const float* __restrict__ bias2,
    __bf16* __restrict__ qo, __bf16* __restrict__ ko, __bf16* __restrict__ vo,
    float* __restrict__ outf) {
  constexpr int K = DMODEL;
  __shared__ __bf16 Alds[128][32];
  __shared__ __bf16 Blds[128][32];
  const int t = threadIdx.x;
  const int lane = t & 63;
  const int wr = (t >> 6) >> 1, wc = (t >> 6) & 1;
  const int bm0 = blockIdx.x * 128, bn0 = blockIdx.y * 128;

  f32x4 acc[4][4] = {};
  for (int k0 = 0; k0 < K; k0 += 32) {
    __syncthreads();
#pragma unroll
    for (int i = 0; i < 2; ++i) {
      int c = t + i * 256;               // 512 x 16B chunks per tile
      int row = c >> 2, kof = (c & 3) << 3;
      gload_lds16(A + (size_t)(bm0 + row) * K + k0 + kof, &Alds[0][0] + c * 8);
      gload_lds16(Bw + (size_t)(bn0 + row) * K + k0 + kof, &Blds[0][0] + c * 8);
    }
    __syncthreads();
    bf16x8 af[4], bfr[4];
#pragma unroll
    for (int m = 0; m < 4; ++m)
      af[m] = *(const bf16x8*)&Alds[wr * 64 + m * 16 + (lane & 15)][(lane >> 4) * 8];
#pragma unroll
    for (int n = 0; n < 4; ++n)
      bfr[n] = *(const bf16x8*)&Blds[wc * 64 + n * 16 + (lane & 15)][(lane >> 4) * 8];
    __builtin_amdgcn_s_setprio(1);
#pragma unroll
    for (int m = 0; m < 4; ++m)
#pragma unroll
      for (int n = 0; n < 4; ++n)
        acc[m][n] = mfma16(af[m], bfr[n], acc[m][n]);
    __builtin_amdgcn_s_setprio(0);
  }

  const int r0 = bm0 + wr * 64, c0 = bn0 + wc * 64;
#pragma unroll
  for (int m = 0; m < 4; ++m) {
#pragma unroll
    for (int n = 0; n < 4; ++n) {
#pragma unroll
      for (int r = 0; r < 4; ++r) {
        int gm = r0 + m * 16 + (lane >> 4) * 4 + r;  // token
        int gn = c0 + n * 16 + (lane & 15);          // output col
        float v = acc[m][n][r];
        if (MODE == 0) {
          int which = gn >> 10, j = gn & 1023;
          int h = j >> 6, d = j & 63;
          int b = gm >> 11, s = gm & 2047;
          size_t off = ((size_t)(b * NHEAD + h) * SEQ + s) * HDIM + d;
          if (which == 0)
            qo[off] = (__bf16)(v + bias0[j]);
          else if (which == 1)
            ko[off] = (__bf16)(v + bias1[j]);
          else
            vo[off] = (__bf16)(v + bias2[j]);
        } else {
          outf[(size_t)gm * DMODEL + gn] = v + bias0[gn];
        }
      }
    }
  }
}

// ------- v (BH,S,Hd) -> vt (BH,Hd,S), LDS-tiled 64x64 transpose -------
__global__ __launch_bounds__(256) void transpose_v(const __bf16* __restrict__ v,
                                                   __bf16* __restrict__ vt) {
  __shared__ __bf16 T[64][80];
  const int s0 = blockIdx.x * 64;
  const int bh = blockIdx.y;
  const int t = threadIdx.x;
  const __bf16* src = v + ((size_t)bh * SEQ + s0) * HDIM;
#pragma unroll
  for (int p = 0; p < 2; ++p) {
    int c = t + p * 256;
    int r = c >> 3, d0 = (c & 7) << 3;
    *(bf16x8*)&T[r][d0] = *(const bf16x8*)(src + (size_t)r * HDIM + d0);
  }
  __syncthreads();
#pragma unroll
  for (int p = 0; p < 2; ++p) {
    int c = t + p * 256;
    int d = c & 63, sc = (c >> 6) << 3;
    bf16x8 o;
#pragma unroll
    for (int j = 0; j < 8; ++j) o[j] = T[sc + j][d];
    *(bf16x8*)(vt + ((size_t)bh * HDIM + d) * SEQ + s0 + sc) = o;
  }
}

// --------------- flash attention, swapped-QK in-register softmax ---------------
// grid: (x = B*H -> XCD pin, y = 16 paired q-tiles of 128 rows). 4 waves x 32 q.
// S^T = mfma(K, Q^T): lane owns q = wq0+(lane&31), 32 keys in regs. Softmax
// in-lane + one lane^32 swap. P repacked to B-frags via cvt_pk + permlane32_swap.
__global__ __launch_bounds__(256) void attn_fwd(const __bf16* __restrict__ qg,
                                                const __bf16* __restrict__ kg,
                                                const __bf16* __restrict__ vtg,
                                                __bf16* __restrict__ att) {
  __shared__ __align__(16) char smem[33280];  // K[2]:16KB | V[2]:16KB ; epi overlay
  const int t = threadIdx.x, lane = t & 63, w = t >> 6, hi = lane >> 5;
  const int bh = blockIdx.x;
  const int yy = blockIdx.y;
  const int qt = (yy < 8) ? yy : 23 - yy;   // pair (qt, 15-qt) per CU: balanced causal load
  const int q0 = qt * 128;
  const int wq0 = q0 + w * 32;
  const int qabs = wq0 + (lane & 31);
  constexpr int NT = SEQ / 64;
  const int kt0 = qt * 2;
  const int ktw = kt0 + (w >> 1);           // first non-fully-masked tile for this wave

  const __bf16* kbase = kg + (size_t)bh * SEQ * HDIM;
  const __bf16* vbase = vtg + (size_t)bh * HDIM * SEQ;

  // Q straight to registers, B-operand layout: col q = lane&31, rows d
  bf16x8 qf[4];
  {
    const __bf16* qptr = qg + ((size_t)bh * SEQ + qabs) * HDIM + hi * 8;
#pragma unroll
    for (int ds = 0; ds < 4; ++ds) qf[ds] = *(const bf16x8*)(qptr + ds * 16);
  }

  auto stage = [&](int kt_, int buf) {
#pragma unroll
    for (int i = 0; i < 2; ++i) {
      int c = t + i * 256;
      int row = c >> 3, sc = (c & 7) ^ (row & 7);
      gload_lds16(kbase + ((size_t)kt_ * 64 + row) * HDIM + sc * 8,
                  (__bf16*)(smem + buf * 8192) + c * 8);
      gload_lds16(vbase + (size_t)row * SEQ + kt_ * 64 + sc * 8,
                  (__bf16*)(smem + 16384 + buf * 8192) + c * 8);
    }
  };

  f32x16 acc0 = {}, acc1 = {};
  float m = -3.0e38f, l = 0.f;
  const float kScale = 0.03125f;  // 1/sqrt(1024)

  stage(kt0, 0);
  __syncthreads();
  int cur = 0;

  for (int kt = kt0; kt < NT; ++kt) {
    if (kt + 1 < NT) stage(kt + 1, cur ^ 1);  // prefetch under this tile's compute
    if (kt >= ktw) {
      const __bf16* Kt = (const __bf16*)(smem + cur * 8192);
      const __bf16* Vw = (const __bf16*)(smem + 16384 + cur * 8192);

      // S^T[key][q] = K · Q^T : two 32-key halves
      f32x16 s0 = {}, s1 = {};
      __builtin_amdgcn_s_setprio(1);
#pragma unroll
      for (int ds = 0; ds < 4; ++ds) {
        s0 = mfma32(*frag128(Kt, lane & 31, 2 * ds + hi), qf[ds], s0);
        s1 = mfma32(*frag128(Kt, 32 + (lane & 31), 2 * ds + hi), qf[ds], s1);
      }
      __builtin_amdgcn_s_setprio(0);

      // causal mask (keep key >= q), only on this wave's diagonal tile
      if (kt == ktw) {
#pragma unroll
        for (int r = 0; r < 16; ++r) {
          int krow = (r & 3) + 8 * (r >> 2) + 4 * hi;
          if (kt * 64 + krow < qabs) s0[r] = -3.0e38f;
          if (kt * 64 + 32 + krow < qabs) s1[r] = -3.0e38f;
        }
      }

      // in-lane max + one cross-half swap
      float pmax = s0[0];
#pragma unroll
      for (int r = 1; r < 16; ++r) pmax = fmaxf(pmax, s0[r]);
#pragma unroll
      for (int r = 0; r < 16; ++r) pmax = fmaxf(pmax, s1[r]);
      pmax = fmaxf(pmax, __shfl_xor(pmax, 32));

      // T13 defer-max: rescale only when max grew > 256 raw (= e^8 in prob space)
      if (pmax > m + 256.0f) {
        float corr = __expf((m - pmax) * kScale);
        m = pmax;
        l *= corr;
#pragma unroll
        for (int r = 0; r < 16; ++r) { acc0[r] *= corr; acc1[r] *= corr; }
      }
      const float bias = m * kScale;
      float sum = 0.f;
#pragma unroll
      for (int r = 0; r < 16; ++r) {
        float p = __expf(fmaf(s0[r], kScale, -bias));
        s0[r] = p; sum += p;
      }
#pragma unroll
      for (int r = 0; r < 16; ++r) {
        float p = __expf(fmaf(s1[r], kScale, -bias));
        s1[r] = p; sum += p;
      }
      sum += __shfl_xor(sum, 32);
      l += sum;

      // repack P (C-layout f32) -> B-operand bf16 frags: cvt_pk + permlane32_swap
      bf16x8 pb[2][2];
#pragma unroll
      for (int h = 0; h < 2; ++h) {
#pragma unroll
        for (int ks = 0; ks < 2; ++ks) {
          int o = ks * 8;
          unsigned a, b, c, d;
          if (h == 0) {
            a = cvtpk(s0[o + 0], s0[o + 1]); b = cvtpk(s0[o + 4], s0[o + 5]);
            c = cvtpk(s0[o + 2], s0[o + 3]); d = cvtpk(s0[o + 6], s0[o + 7]);
          } else {
            a = cvtpk(s1[o + 0], s1[o + 1]); b = cvtpk(s1[o + 4], s1[o + 5]);
            c = cvtpk(s1[o + 2], s1[o + 3]); d = cvtpk(s1[o + 6], s1[o + 7]);
          }
          plswap(a, b);  // lo: keeps rows(0,1); hi: gets rows(8,9) | b -> rows(4,5)/(12,13)
          plswap(c, d);
          union { u32x4 u; bf16x8 v; } f;
          f.u[0] = a; f.u[1] = c; f.u[2] = b; f.u[3] = d;
          pb[h][ks] = f.v;
        }
      }

      // O^T[d][q] += V^T · P^T
      __builtin_amdgcn_s_setprio(1);
#pragma unroll
      for (int h = 0; h < 2; ++h)
#pragma unroll
        for (int ks = 0; ks < 2; ++ks) {
          int cc = h * 4 + ks * 2 + hi;
          acc0 = mfma32(*frag128(Vw, lane & 31, cc), pb[h][ks], acc0);
          acc1 = mfma32(*frag128(Vw, 32 + (lane & 31), cc), pb[h][ks], acc1);
        }
      __builtin_amdgcn_s_setprio(0);
    }
    __syncthreads();  // drains prefetch, protects buffer swap
    cur ^= 1;
  }

  // epilogue: O^T -> LDS (stride 65: conflict-free) -> coalesced bf16x8 stores
  float inv = 1.0f / l;
  float* Ow = (float*)smem + w * 2080;
#pragma unroll
  for (int r = 0; r < 16; ++r) {
    int d = (r & 3) + 8 * (r >> 2) + 4 * hi;
    Ow[(lane & 31) * 65 + d] = acc0[r] * inv;
    Ow[(lane & 31) * 65 + 32 + d] = acc1[r] * inv;
  }
  const int b = bh >> 4, hd = bh & 15;
#pragma unroll
  for (int j = 0; j < 4; ++j) {
    int f = j * 64 + lane;
    int q = f >> 3, c8 = f & 7;
    const float* src = Ow + q * 65 + c8 * 8;
    bf16x8 o;
#pragma unroll
    for (int e = 0; e < 8; ++e) o[e] = (__bf16)src[e];
    *(bf16x8*)(att + ((size_t)(b * SEQ + q0 + w * 32 + q)) * DMODEL + hd * HDIM + c8 * 8) = o;
  }
}

extern "C" void kernel_launch(void* const* d_in, const int* in_sizes, int n_in,
                              void* d_out, int out_size, void* d_ws, size_t ws_size,
                              hipStream_t stream) {
  (void)in_sizes; (void)n_in; (void)out_size;
  const float* x  = (const float*)d_in[0];
  const float* Wq = (const float*)d_in[1];
  const float* bq = (const float*)d_in[2];
  const float* Wk = (const float*)d_in[3];
  const float* bk = (const float*)d_in[4];
  const float* Wv = (const float*)d_in[5];
  const float* bv = (const float*)d_in[6];
  const float* Wo = (const float*)d_in[7];
  const float* bo = (const float*)d_in[8];
  float* out = (float*)d_out;

  const size_t SZ_X = (size_t)BTOK * DMODEL;  // 4M elems
  const size_t SZ_W = (size_t)DMODEL * DMODEL;
  const size_t SZ_H = (size_t)32 * SEQ * HDIM;  // B*H * S * Hd

  char* p = (char*)d_ws;
  __bf16* x_bf  = (__bf16*)p; p += SZ_X * 2;   // reused as vt after gemm<0>
  __bf16* wqkv  = (__bf16*)p; p += 3 * SZ_W * 2;
  __bf16* wo_bf = (__bf16*)p; p += SZ_W * 2;   // contiguous after wqkv (cvt4 relies on it)
  __bf16* q_bf  = (__bf16*)p; p += SZ_H * 2;
  __bf16* k_bf  = (__bf16*)p; p += SZ_H * 2;
  __bf16* v_bf  = (__bf16*)p; p += SZ_H * 2;
  __bf16* at_bf = (__bf16*)p; p += SZ_X * 2;
  if ((size_t)(p - (char*)d_ws) > ws_size) return;
  __bf16* vt_bf = x_bf;  // x dead after gemm<0>

  cvt_f32_bf16<<<(unsigned)(SZ_X / 8 / 256), 256, 0, stream>>>(x, x_bf, (int)(SZ_X / 8));
  cvt4_f32_bf16<<<dim3((unsigned)(SZ_W / 8 / 256), 4), 256, 0, stream>>>(
      Wq, Wk, Wv, Wo, wqkv, (int)(SZ_W / 8));

  gemm_bt<0><<<dim3(BTOK / 128, NQKV / 128), 256, 0, stream>>>(
      x_bf, wqkv, bq, bk, bv, q_bf, k_bf, v_bf, nullptr);
  transpose_v<<<dim3(SEQ / 64, 32), 256, 0, stream>>>(v_bf, vt_bf);
  attn_fwd<<<dim3(32, 16), 256, 0, stream>>>(q_bf, k_bf, vt_bf, at_bf);
  gemm_bt<1><<<dim3(BTOK / 128, DMODEL / 128), 256, 0, stream>>>(
      at_bf, wo_bf, bo, nullptr, nullptr, nullptr, nullptr, nullptr, out);
}

// Round 5
// 198.169 us; speedup vs baseline: 1.3908x; 1.0124x over previous
//
#include <hip/hip_runtime.h>
#include <stdint.h>

typedef __attribute__((ext_vector_type(8))) __bf16 bf16x8;
typedef __attribute__((ext_vector_type(4))) float f32x4;
typedef __attribute__((ext_vector_type(16))) float f32x16;
typedef __attribute__((ext_vector_type(4))) unsigned u32x4;

#define SEQ 2048
#define DMODEL 1024
#define NHEAD 16
#define HDIM 64
#define BTOK 4096   // B*S
#define NQKV 3072   // stacked q,k,v output cols

// ---- async global->LDS, 16B per lane; LDS dest must be wave-linear ----
__device__ __forceinline__ void gload_lds16(const __bf16* g, __bf16* l) {
  __builtin_amdgcn_global_load_lds(
      (__attribute__((address_space(1))) void*)const_cast<__bf16*>(g),
      (__attribute__((address_space(3))) void*)l, 16, 0, 0);
}

__device__ __forceinline__ f32x4 mfma16(bf16x8 a, bf16x8 b, f32x4 c) {
  return __builtin_amdgcn_mfma_f32_16x16x32_bf16(a, b, c, 0, 0, 0);
}
__device__ __forceinline__ f32x16 mfma32(bf16x8 a, bf16x8 b, f32x16 c) {
  return __builtin_amdgcn_mfma_f32_32x32x16_bf16(a, b, c, 0, 0, 0);
}

// pack 2 f32 -> 1 u32 of 2 bf16 (lo in low half)
__device__ __forceinline__ unsigned cvtpk(float lo, float hi) {
  unsigned r;
  asm("v_cvt_pk_bf16_f32 %0, %1, %2" : "=v"(r) : "v"(lo), "v"(hi));
  return r;
}
// swap a's lanes 32-63 with b's lanes 0-31 (in place)
__device__ __forceinline__ void plswap(unsigned& a, unsigned& b) {
  asm volatile("v_permlane32_swap_b32 %0, %1" : "+v"(a), "+v"(b));
}

// swizzled 16B-fragment pointer into a tile with 128B rows (64 bf16/row).
__device__ __forceinline__ const bf16x8* frag128(const __bf16* tile, int row, int c16) {
  return reinterpret_cast<const bf16x8*>(tile) + ((row << 3) + (c16 ^ (row & 7)));
}

// ---------------- fp32 -> bf16 convert, 8 elems/thread ----------------
__global__ __launch_bounds__(256) void cvt_f32_bf16(const float* __restrict__ in,
                                                    __bf16* __restrict__ out, int n8) {
  int i = blockIdx.x * 256 + threadIdx.x;
  if (i >= n8) return;
  const float4* p = reinterpret_cast<const float4*>(in) + (size_t)i * 2;
  float4 a = p[0], b = p[1];
  bf16x8 o;
  o[0] = (__bf16)a.x; o[1] = (__bf16)a.y; o[2] = (__bf16)a.z; o[3] = (__bf16)a.w;
  o[4] = (__bf16)b.x; o[5] = (__bf16)b.y; o[6] = (__bf16)b.z; o[7] = (__bf16)b.w;
  reinterpret_cast<bf16x8*>(out)[i] = o;
}

// ---- 4 weight matrices (Wq,Wk,Wv,Wo) -> contiguous bf16 in one launch ----
__global__ __launch_bounds__(256) void cvt4_f32_bf16(const float* __restrict__ w0,
                                                     const float* __restrict__ w1,
                                                     const float* __restrict__ w2,
                                                     const float* __restrict__ w3,
                                                     __bf16* __restrict__ out, int n8per) {
  const int y = blockIdx.y;
  const float* src = (y == 0) ? w0 : (y == 1) ? w1 : (y == 2) ? w2 : w3;
  int i = blockIdx.x * 256 + threadIdx.x;
  if (i >= n8per) return;
  const float4* p = reinterpret_cast<const float4*>(src) + (size_t)i * 2;
  float4 a = p[0], b = p[1];
  bf16x8 o;
  o[0] = (__bf16)a.x; o[1] = (__bf16)a.y; o[2] = (__bf16)a.z; o[3] = (__bf16)a.w;
  o[4] = (__bf16)b.x; o[5] = (__bf16)b.y; o[6] = (__bf16)b.z; o[7] = (__bf16)b.w;
  reinterpret_cast<bf16x8*>(out)[(size_t)y * n8per + i] = o;
}

// ------ C = A(4096xK) * Bw(NxK)^T + bias, 2-phase prefetch dbuf ------
// MODE 0: N=3072, scatter into q,k,v natural (B,H,S,Hd) bf16
// MODE 1: N=1024, fp32 out + bias
template <int MODE>
__global__ __launch_bounds__(256) void gemm_bt(
    const __bf16* __restrict__ A, const __bf16* __restrict__ Bw,
    const float* __restrict__ bias0, const float* __restrict__ bias1,
    const float* __restrict__ bias2,
    __bf16* __restrict__ qo, __bf16* __restrict__ ko, __bf16* __restrict__ vo,
    float* __restrict__ outf) {
  constexpr int K = DMODEL;
  __shared__ __bf16 Alds[2][128][32];
  __shared__ __bf16 Blds[2][128][32];
  const int t = threadIdx.x;
  const int lane = t & 63;
  const int wr = (t >> 6) >> 1, wc = (t >> 6) & 1;
  const int bm0 = blockIdx.x * 128, bn0 = blockIdx.y * 128;

  auto stageg = [&](int k0, int buf) {
#pragma unroll
    for (int i = 0; i < 2; ++i) {
      int c = t + i * 256;               // 512 x 16B chunks per tile
      int row = c >> 2, kof = (c & 3) << 3;
      gload_lds16(A + (size_t)(bm0 + row) * K + k0 + kof, &Alds[buf][0][0] + c * 8);
      gload_lds16(Bw + (size_t)(bn0 + row) * K + k0 + kof, &Blds[buf][0][0] + c * 8);
    }
  };

  f32x4 acc[4][4] = {};
  stageg(0, 0);
  __syncthreads();
  int cur = 0;
  for (int k0 = 0; k0 < K; k0 += 32) {
    if (k0 + 32 < K) stageg(k0 + 32, cur ^ 1);  // prefetch hides under compute
    bf16x8 af[4], bfr[4];
#pragma unroll
    for (int m = 0; m < 4; ++m)
      af[m] = *(const bf16x8*)&Alds[cur][wr * 64 + m * 16 + (lane & 15)][(lane >> 4) * 8];
#pragma unroll
    for (int n = 0; n < 4; ++n)
      bfr[n] = *(const bf16x8*)&Blds[cur][wc * 64 + n * 16 + (lane & 15)][(lane >> 4) * 8];
    __builtin_amdgcn_s_setprio(1);
#pragma unroll
    for (int m = 0; m < 4; ++m)
#pragma unroll
      for (int n = 0; n < 4; ++n)
        acc[m][n] = mfma16(af[m], bfr[n], acc[m][n]);
    __builtin_amdgcn_s_setprio(0);
    __syncthreads();  // drains prefetch vmcnt + protects buffer reuse
    cur ^= 1;
  }

  const int r0 = bm0 + wr * 64, c0 = bn0 + wc * 64;
#pragma unroll
  for (int m = 0; m < 4; ++m) {
#pragma unroll
    for (int n = 0; n < 4; ++n) {
#pragma unroll
      for (int r = 0; r < 4; ++r) {
        int gm = r0 + m * 16 + (lane >> 4) * 4 + r;  // token
        int gn = c0 + n * 16 + (lane & 15);          // output col
        float v = acc[m][n][r];
        if (MODE == 0) {
          int which = gn >> 10, j = gn & 1023;
          int h = j >> 6, d = j & 63;
          int b = gm >> 11, s = gm & 2047;
          size_t off = ((size_t)(b * NHEAD + h) * SEQ + s) * HDIM + d;
          if (which == 0)
            qo[off] = (__bf16)(v + bias0[j]);
          else if (which == 1)
            ko[off] = (__bf16)(v + bias1[j]);
          else
            vo[off] = (__bf16)(v + bias2[j]);
        } else {
          outf[(size_t)gm * DMODEL + gn] = v + bias0[gn];
        }
      }
    }
  }
}

// ------- v (BH,S,Hd) -> vt (BH,Hd,S), LDS-tiled 64x64 transpose -------
__global__ __launch_bounds__(256) void transpose_v(const __bf16* __restrict__ v,
                                                   __bf16* __restrict__ vt) {
  __shared__ __bf16 T[64][80];
  const int s0 = blockIdx.x * 64;
  const int bh = blockIdx.y;
  const int t = threadIdx.x;
  const __bf16* src = v + ((size_t)bh * SEQ + s0) * HDIM;
#pragma unroll
  for (int p = 0; p < 2; ++p) {
    int c = t + p * 256;
    int r = c >> 3, d0 = (c & 7) << 3;
    *(bf16x8*)&T[r][d0] = *(const bf16x8*)(src + (size_t)r * HDIM + d0);
  }
  __syncthreads();
#pragma unroll
  for (int p = 0; p < 2; ++p) {
    int c = t + p * 256;
    int d = c & 63, sc = (c >> 6) << 3;
    bf16x8 o;
#pragma unroll
    for (int j = 0; j < 8; ++j) o[j] = T[sc + j][d];
    *(bf16x8*)(vt + ((size_t)bh * HDIM + d) * SEQ + s0 + sc) = o;
  }
}

// --------------- flash attention, swapped-QK in-register softmax ---------------
// grid: (x = B*H -> XCD pin, y = 32 paired q-tiles of 64 rows). 2 waves x 32 q.
__global__ __launch_bounds__(128) void attn_fwd(const __bf16* __restrict__ qg,
                                                const __bf16* __restrict__ kg,
                                                const __bf16* __restrict__ vtg,
                                                __bf16* __restrict__ att) {
  __shared__ __align__(16) char smem[32768];  // K[2]:16KB | V[2]:16KB ; epi overlay
  const int t = threadIdx.x, lane = t & 63, w = t >> 6, hi = lane >> 5;
  const int bh = blockIdx.x;
  const int yy = blockIdx.y;
  const int qt = (yy < 16) ? yy : 47 - yy;   // pair (qt, 31-qt): balanced causal load
  const int q0 = qt * 64;
  const int qabs = q0 + w * 32 + (lane & 31);
  constexpr int NT = SEQ / 64;

  const __bf16* kbase = kg + (size_t)bh * SEQ * HDIM;
  const __bf16* vbase = vtg + (size_t)bh * HDIM * SEQ;

  // Q straight to registers, B-operand layout: col q = lane&31, rows d
  bf16x8 qf[4];
  {
    const __bf16* qptr = qg + ((size_t)bh * SEQ + qabs) * HDIM + hi * 8;
#pragma unroll
    for (int ds = 0; ds < 4; ++ds) qf[ds] = *(const bf16x8*)(qptr + ds * 16);
  }

  auto stage = [&](int kt_, int buf) {
#pragma unroll
    for (int i = 0; i < 4; ++i) {
      int c = t + i * 128;
      int row = c >> 3, sc = (c & 7) ^ (row & 7);
      gload_lds16(kbase + ((size_t)kt_ * 64 + row) * HDIM + sc * 8,
                  (__bf16*)(smem + buf * 8192) + c * 8);
      gload_lds16(vbase + (size_t)row * SEQ + kt_ * 64 + sc * 8,
                  (__bf16*)(smem + 16384 + buf * 8192) + c * 8);
    }
  };

  f32x16 acc0 = {}, acc1 = {};
  float m = -3.0e38f, l = 0.f;
  const float kScale = 0.03125f;  // 1/sqrt(1024)

  stage(qt, 0);
  __syncthreads();
  int cur = 0;

  for (int kt = qt; kt < NT; ++kt) {
    if (kt + 1 < NT) stage(kt + 1, cur ^ 1);  // prefetch under this tile's compute
    const __bf16* Kt = (const __bf16*)(smem + cur * 8192);
    const __bf16* Vw = (const __bf16*)(smem + 16384 + cur * 8192);

    // S^T[key][q] = K · Q^T : two 32-key halves
    f32x16 s0 = {}, s1 = {};
    __builtin_amdgcn_s_setprio(1);
#pragma unroll
    for (int ds = 0; ds < 4; ++ds) {
      s0 = mfma32(*frag128(Kt, lane & 31, 2 * ds + hi), qf[ds], s0);
      s1 = mfma32(*frag128(Kt, 32 + (lane & 31), 2 * ds + hi), qf[ds], s1);
    }
    __builtin_amdgcn_s_setprio(0);

    // causal mask (keep key >= q): only the diagonal tile is partial
    if (kt == qt) {
#pragma unroll
      for (int r = 0; r < 16; ++r) {
        int krow = (r & 3) + 8 * (r >> 2) + 4 * hi;
        if (kt * 64 + krow < qabs) s0[r] = -3.0e38f;
        if (kt * 64 + 32 + krow < qabs) s1[r] = -3.0e38f;
      }
    }

    // max: depth-5 tree + one cross-half swap
    float mt[8];
#pragma unroll
    for (int r = 0; r < 8; ++r)
      mt[r] = fmaxf(fmaxf(s0[r], s0[r + 8]), fmaxf(s1[r], s1[r + 8]));
#pragma unroll
    for (int r = 0; r < 4; ++r) mt[r] = fmaxf(mt[r], mt[r + 4]);
    float pmax = fmaxf(fmaxf(mt[0], mt[2]), fmaxf(mt[1], mt[3]));
    pmax = fmaxf(pmax, __shfl_xor(pmax, 32));

    // T13 defer-max, wave-uniform: rescale only if any lane's max grew > 256 raw (e^8)
    if (!__all(pmax - m <= 256.0f)) {
      float newm = fmaxf(m, pmax);
      float corr = __expf((m - newm) * kScale);
      m = newm;
      l *= corr;
#pragma unroll
      for (int r = 0; r < 16; ++r) { acc0[r] *= corr; acc1[r] *= corr; }
    }
    const float bias = m * kScale;
#pragma unroll
    for (int r = 0; r < 16; ++r) s0[r] = __expf(fmaf(s0[r], kScale, -bias));
#pragma unroll
    for (int r = 0; r < 16; ++r) s1[r] = __expf(fmaf(s1[r], kScale, -bias));
    // sum: depth-5 tree (float add not reassociable -> hand-tree)
    float ut[8];
#pragma unroll
    for (int r = 0; r < 8; ++r) ut[r] = (s0[r] + s0[r + 8]) + (s1[r] + s1[r + 8]);
#pragma unroll
    for (int r = 0; r < 4; ++r) ut[r] += ut[r + 4];
    float sum = (ut[0] + ut[2]) + (ut[1] + ut[3]);
    sum += __shfl_xor(sum, 32);
    l += sum;

    // repack P (C-layout f32) -> B-operand bf16 frags: cvt_pk + permlane32_swap
    bf16x8 pb[2][2];
#pragma unroll
    for (int h = 0; h < 2; ++h) {
#pragma unroll
      for (int ks = 0; ks < 2; ++ks) {
        int o = ks * 8;
        unsigned a, b, c, d;
        if (h == 0) {
          a = cvtpk(s0[o + 0], s0[o + 1]); b = cvtpk(s0[o + 4], s0[o + 5]);
          c = cvtpk(s0[o + 2], s0[o + 3]); d = cvtpk(s0[o + 6], s0[o + 7]);
        } else {
          a = cvtpk(s1[o + 0], s1[o + 1]); b = cvtpk(s1[o + 4], s1[o + 5]);
          c = cvtpk(s1[o + 2], s1[o + 3]); d = cvtpk(s1[o + 6], s1[o + 7]);
        }
        plswap(a, b);
        plswap(c, d);
        union { u32x4 u; bf16x8 v; } f;
        f.u[0] = a; f.u[1] = c; f.u[2] = b; f.u[3] = d;
        pb[h][ks] = f.v;
      }
    }

    // O^T[d][q] += V^T · P^T
    __builtin_amdgcn_s_setprio(1);
#pragma unroll
    for (int h = 0; h < 2; ++h)
#pragma unroll
      for (int ks = 0; ks < 2; ++ks) {
        int cc = h * 4 + ks * 2 + hi;
        acc0 = mfma32(*frag128(Vw, lane & 31, cc), pb[h][ks], acc0);
        acc1 = mfma32(*frag128(Vw, 32 + (lane & 31), cc), pb[h][ks], acc1);
      }
    __builtin_amdgcn_s_setprio(0);

    __syncthreads();  // drains prefetch, protects buffer swap
    cur ^= 1;
  }

  // epilogue: O^T -> LDS (stride 65: conflict-free) -> coalesced bf16x8 stores
  float inv = 1.0f / l;
  float* Ow = (float*)smem + (size_t)w * 2080;
#pragma unroll
  for (int r = 0; r < 16; ++r) {
    int d = (r & 3) + 8 * (r >> 2) + 4 * hi;
    Ow[(lane & 31) * 65 + d] = acc0[r] * inv;
    Ow[(lane & 31) * 65 + 32 + d] = acc1[r] * inv;
  }
  const int b = bh >> 4, hd = bh & 15;
#pragma unroll
  for (int j = 0; j < 4; ++j) {
    int f = j * 64 + lane;
    int q = f >> 3, c8 = f & 7;
    const float* src = Ow + q * 65 + c8 * 8;
    bf16x8 o;
#pragma unroll
    for (int e = 0; e < 8; ++e) o[e] = (__bf16)src[e];
    *(bf16x8*)(att + ((size_t)(b * SEQ + q0 + w * 32 + q)) * DMODEL + hd * HDIM + c8 * 8) = o;
  }
}

extern "C" void kernel_launch(void* const* d_in, const int* in_sizes, int n_in,
                              void* d_out, int out_size, void* d_ws, size_t ws_size,
                              hipStream_t stream) {
  (void)in_sizes; (void)n_in; (void)out_size;
  const float* x  = (const float*)d_in[0];
  const float* Wq = (const float*)d_in[1];
  const float* bq = (const float*)d_in[2];
  const float* Wk = (const float*)d_in[3];
  const float* bk = (const float*)d_in[4];
  const float* Wv = (const float*)d_in[5];
  const float* bv = (const float*)d_in[6];
  const float* Wo = (const float*)d_in[7];
  const float* bo = (const float*)d_in[8];
  float* out = (float*)d_out;

  const size_t SZ_X = (size_t)BTOK * DMODEL;  // 4M elems
  const size_t SZ_W = (size_t)DMODEL * DMODEL;
  const size_t SZ_H = (size_t)32 * SEQ * HDIM;  // B*H * S * Hd

  char* p = (char*)d_ws;
  __bf16* x_bf  = (__bf16*)p; p += SZ_X * 2;   // reused as vt after gemm<0>
  __bf16* wqkv  = (__bf16*)p; p += 3 * SZ_W * 2;
  __bf16* wo_bf = (__bf16*)p; p += SZ_W * 2;   // contiguous after wqkv (cvt4 relies on it)
  __bf16* q_bf  = (__bf16*)p; p += SZ_H * 2;
  __bf16* k_bf  = (__bf16*)p; p += SZ_H * 2;
  __bf16* v_bf  = (__bf16*)p; p += SZ_H * 2;
  __bf16* at_bf = (__bf16*)p; p += SZ_X * 2;
  if ((size_t)(p - (char*)d_ws) > ws_size) return;
  __bf16* vt_bf = x_bf;  // x dead after gemm<0>

  cvt_f32_bf16<<<(unsigned)(SZ_X / 8 / 256), 256, 0, stream>>>(x, x_bf, (int)(SZ_X / 8));
  cvt4_f32_bf16<<<dim3((unsigned)(SZ_W / 8 / 256), 4), 256, 0, stream>>>(
      Wq, Wk, Wv, Wo, wqkv, (int)(SZ_W / 8));

  gemm_bt<0><<<dim3(BTOK / 128, NQKV / 128), 256, 0, stream>>>(
      x_bf, wqkv, bq, bk, bv, q_bf, k_bf, v_bf, nullptr);
  transpose_v<<<dim3(SEQ / 64, 32), 256, 0, stream>>>(v_bf, vt_bf);
  attn_fwd<<<dim3(32, 32), 128, 0, stream>>>(q_bf, k_bf, vt_bf, at_bf);
  gemm_bt<1><<<dim3(BTOK / 128, DMODEL / 128), 256, 0, stream>>>(
      at_bf, wo_bf, bo, nullptr, nullptr, nullptr, nullptr, nullptr, out);
}